// Round 2
// baseline (102.161 us; speedup 1.0000x reference)
//
#include <hip/hip_runtime.h>
#include <hip/hip_bf16.h>
#include <cstdint>
#include <cstddef>

#define DIMC 1024
#define HEADS 16
#define HD 64
#define WINDOW 128
#define BB 2
#define TT 2048
#define NTOK (BB*TT)       // 4096
#define QKVN (3*DIMC)      // 3072

typedef __bf16 bf16;
typedef __bf16 bf16x8 __attribute__((ext_vector_type(8)));
typedef __bf16 bf16x4 __attribute__((ext_vector_type(4)));
typedef float f32x4 __attribute__((ext_vector_type(4)));
typedef unsigned int u32;

typedef const __attribute__((address_space(1))) u32* gp1_t;
typedef __attribute__((address_space(3))) u32* lp3_t;

__device__ __forceinline__ void gload16(const void* g, void* l) {
  // async global->LDS, 16B per lane; LDS dest = wave-uniform base + lane*16
  __builtin_amdgcn_global_load_lds((gp1_t)g, (lp3_t)l, 16, 0, 0);
}

// ---------------------------------------------------------------- cast kernel
__global__ void cast3_kernel(const float* __restrict__ x,
                             const float* __restrict__ wq,
                             const float* __restrict__ wp,
                             bf16* __restrict__ xo,
                             bf16* __restrict__ wqo,
                             bf16* __restrict__ wpo) {
  const int NX = NTOK * DIMC / 4;
  const int NQ = QKVN * DIMC / 4;
  const int NP = DIMC * DIMC / 4;
  const int total = NX + NQ + NP;
  typedef float float4v __attribute__((ext_vector_type(4)));
  for (int i = blockIdx.x * blockDim.x + threadIdx.x; i < total;
       i += gridDim.x * blockDim.x) {
    const float4v* src; bf16* dst; int j;
    if (i < NX)            { src = (const float4v*)x;  dst = xo;  j = i; }
    else if (i < NX + NQ)  { src = (const float4v*)wq; dst = wqo; j = i - NX; }
    else                   { src = (const float4v*)wp; dst = wpo; j = i - NX - NQ; }
    float4v v = src[j];
    bf16x4 o;
    o[0] = (bf16)v[0]; o[1] = (bf16)v[1]; o[2] = (bf16)v[2]; o[3] = (bf16)v[3];
    ((bf16x4*)dst)[j] = o;
  }
}

// ---------------------------------------------------------------- 256x256 8-phase GEMM (C = A * B^T, bf16 out)
// A: [M][1024] bf16, Bw: [N_][1024] bf16 (weight layout). 256x256 tile, BK=64,
// 8 waves (2Mx4N), 512 thr. st_16x32 LDS swizzle both-sides. Counted vmcnt(6).
__device__ __forceinline__ bf16x8 lds_frag(const bf16* base, int row, int colb) {
  // logical (row, byte-col) -> swizzled: colb ^= (row&4)<<3  (st_16x32)
  const char* p = (const char*)base + row * 128 + (colb ^ ((row & 4) << 3));
  return *(const bf16x8*)p;
}

__global__ __launch_bounds__(512, 2) void gemm256_qkv_kernel(
    const bf16* __restrict__ A, const bf16* __restrict__ Bw,
    bf16* __restrict__ C) {
  constexpr int K = 1024;
  constexpr int NT = K / 64;             // 16 K-tiles
  __shared__ bf16 Alds[2][256 * 64];
  __shared__ bf16 Blds[2][256 * 64];

  const int tid = threadIdx.x;
  const int wid = tid >> 6, l = tid & 63;
  const int wm = wid >> 2, wn = wid & 3;
  const int lr = l & 15, lg = l >> 4;
  const int w8 = wid * 8;

  // XCD-aware swizzle: 192 blocks, 192 % 8 == 0 -> simple form valid
  const int bid = blockIdx.x;
  const int wg = (bid & 7) * 24 + (bid >> 3);
  const int bm = wg & 15;                // M/256 = 16
  const int bn = wg >> 4;                // N/256 = 12

  const char* Ag = (const char*)A + (size_t)(bm * 256) * 2048;
  const char* Bg = (const char*)Bw + (size_t)(bn * 256) * 2048;

  // stage one half-tile (128 rows x 64 cols) of matrix into LDS buffer.
  // half 0 = rows {0-63, 128-191}; half 1 = rows {64-127, 192-255}.
  // dest linear; global source pre-swizzled (inverse of read swizzle).
  auto stage = [&](bf16* lds, const char* gbase, int kt, int half) {
#pragma unroll
    for (int i = 0; i < 2; i++) {
      const int R0 = half * 64 + i * 128 + w8;       // wave-uniform
      const int r = R0 + (l >> 3);
      const char* src = gbase + (size_t)r * 2048 + kt * 128
                        + (((l & 7) * 16) ^ ((r & 4) << 3));
      gload16(src, lds + R0 * 64);
    }
  };

  // ---- prologue: B0(k0) B1(k0) A0(k0) A1(k0) B0(k1) B1(k1) A0(k1)
  stage(Blds[0], Bg, 0, 0);
  stage(Blds[0], Bg, 0, 1);
  stage(Alds[0], Ag, 0, 0);
  stage(Alds[0], Ag, 0, 1);
  stage(Blds[1], Bg, 1, 0);
  stage(Blds[1], Bg, 1, 1);
  stage(Alds[1], Ag, 1, 0);
  asm volatile("s_waitcnt vmcnt(6)" ::: "memory");
  __builtin_amdgcn_s_barrier();

  f32x4 acc[8][4] = {};

  // one K-tile: 4 phases of {ds_read, stage, bar, lgkm(0), 16 MFMA, [vmcnt], bar}
  auto ktile = [&](int kt, const bf16* Acur, const bf16* Bcur,
                   bf16* Anext, bf16* Bnext, bf16* Acur_w, bf16* Bcur_w) {
    bf16x8 bfr[4][2];
#pragma unroll
    for (int mq = 0; mq < 4; ++mq) {
      if (mq == 0) {
#pragma unroll
        for (int n = 0; n < 4; n++)
#pragma unroll
          for (int kk = 0; kk < 2; kk++)
            bfr[n][kk] = lds_frag(Bcur, wn * 64 + n * 16 + lr, kk * 64 + lg * 16);
      }
      bf16x8 afr[2][2];
#pragma unroll
      for (int mi = 0; mi < 2; mi++)
#pragma unroll
        for (int kk = 0; kk < 2; kk++)
          afr[mi][kk] = lds_frag(Acur, wm * 128 + (2 * mq + mi) * 16 + lr,
                                 kk * 64 + lg * 16);
      // staging pattern: ph0: A-h1(kt+1); ph1: B-h0(kt+2); ph2: B-h1(kt+2); ph3: A-h0(kt+2)
      if (mq == 0)      { if (kt + 1 < NT) stage(Anext,  Ag, kt + 1, 1); }
      else if (mq == 1) { if (kt + 2 < NT) stage(Bcur_w, Bg, kt + 2, 0); }
      else if (mq == 2) { if (kt + 2 < NT) stage(Bcur_w, Bg, kt + 2, 1); }
      else              { if (kt + 2 < NT) stage(Acur_w, Ag, kt + 2, 0); }
      asm volatile("" ::: "memory");
      __builtin_amdgcn_s_barrier();
      asm volatile("s_waitcnt lgkmcnt(0)" ::: "memory");
      __builtin_amdgcn_s_setprio(1);
#pragma unroll
      for (int kk = 0; kk < 2; kk++)
#pragma unroll
        for (int mi = 0; mi < 2; mi++)
#pragma unroll
          for (int n = 0; n < 4; n++)
            acc[2 * mq + mi][n] = __builtin_amdgcn_mfma_f32_16x16x32_bf16(
                afr[mi][kk], bfr[n][kk], acc[2 * mq + mi][n], 0, 0, 0);
      __builtin_amdgcn_s_setprio(0);
      if (mq == 3) {
        if (kt == NT - 2) asm volatile("s_waitcnt vmcnt(0)" ::: "memory");
        else              asm volatile("s_waitcnt vmcnt(6)" ::: "memory");
      }
      asm volatile("" ::: "memory");
      __builtin_amdgcn_s_barrier();
    }
  };

  for (int kt2 = 0; kt2 < NT; kt2 += 2) {
    ktile(kt2,     Alds[0], Blds[0], Alds[1], Blds[1], Alds[0], Blds[0]);
    ktile(kt2 + 1, Alds[1], Blds[1], Alds[0], Blds[0], Alds[1], Blds[1]);
  }

  // ---- epilogue: frag row = lg*4+j, col = lr
#pragma unroll
  for (int m = 0; m < 8; m++) {
    const int row = bm * 256 + wm * 128 + m * 16 + lg * 4;
#pragma unroll
    for (int n = 0; n < 4; n++) {
      const int col = bn * 256 + wn * 64 + n * 16 + lr;
#pragma unroll
      for (int j = 0; j < 4; j++)
        C[(size_t)(row + j) * QKVN + col] = (bf16)acc[m][n][j];
    }
  }
}

// ---------------------------------------------------------------- 128x128 GEMM (proj, fp32 out + bias)
template<int N_>
__global__ __launch_bounds__(256, 2) void gemm_bt_kernel(
    const bf16* __restrict__ A, const bf16* __restrict__ Bw,
    float* __restrict__ Cf, const float* __restrict__ bias) {
  constexpr int K = 1024;
  constexpr int KB = K * 2;
  __shared__ bf16 As[2][128 * 32];
  __shared__ bf16 Bs[2][128 * 32];

  const int tid = threadIdx.x;
  const int w = tid >> 6, l = tid & 63;
  const int bm = blockIdx.x & 31;
  const int bn = blockIdx.x >> 5;
  const int wm = w >> 1, wn = w & 1;
  const int lr = l & 15, lg = l >> 4;

  const int srow = w * 32 + (l >> 2);
  const int scolb = (l & 3) * 16;
  const char* Agb = (const char*)A + (size_t)(bm * 128 + srow) * KB + scolb;
  const char* Bgb = (const char*)Bw + (size_t)(bn * 128 + srow) * KB + scolb;

  f32x4 acc[4][4] = {};

  auto stage = [&](int buf, int t) {
    const char* ag = Agb + t * 64;
    const char* bg = Bgb + t * 64;
    gload16(ag,            &As[buf][(w * 32) * 32]);
    gload16(ag + 16 * KB,  &As[buf][(w * 32 + 16) * 32]);
    gload16(bg,            &Bs[buf][(w * 32) * 32]);
    gload16(bg + 16 * KB,  &Bs[buf][(w * 32 + 16) * 32]);
  };

  stage(0, 0);
  __syncthreads();
  constexpr int NTiles = K / 32;
  int buf = 0;
  for (int t = 0; t < NTiles; ++t) {
    if (t + 1 < NTiles) stage(buf ^ 1, t + 1);
    bf16x8 af[4], bfr[4];
#pragma unroll
    for (int m = 0; m < 4; m++)
      af[m] = *(const bf16x8*)&As[buf][(wm * 64 + m * 16 + lr) * 32 + lg * 8];
#pragma unroll
    for (int n = 0; n < 4; n++)
      bfr[n] = *(const bf16x8*)&Bs[buf][(wn * 64 + n * 16 + lr) * 32 + lg * 8];
#pragma unroll
    for (int m = 0; m < 4; m++)
#pragma unroll
      for (int n = 0; n < 4; n++)
        acc[m][n] = __builtin_amdgcn_mfma_f32_16x16x32_bf16(af[m], bfr[n], acc[m][n], 0, 0, 0);
    __syncthreads();
    buf ^= 1;
  }

#pragma unroll
  for (int m = 0; m < 4; m++) {
    const int row = bm * 128 + wm * 64 + m * 16 + lg * 4;
#pragma unroll
    for (int n = 0; n < 4; n++) {
      const int col = bn * 128 + wn * 64 + n * 16 + lr;
#pragma unroll
      for (int j = 0; j < 4; j++)
        Cf[(size_t)(row + j) * N_ + col] = acc[m][n][j] + bias[col];
    }
  }
}

// ---------------------------------------------------------------- attention
__global__ __launch_bounds__(256, 2) void attn_kernel(const bf16* __restrict__ qkv,
                                                      bf16* __restrict__ out) {
  __shared__ bf16 Kl[64][72];
  __shared__ bf16 Vt[64][72];
  __shared__ bf16 Pl[4][16][72];

  const int tid = threadIdx.x, w = tid >> 6, l = tid & 63;
  const int qb = blockIdx.x & 31, bh = blockIdx.x >> 5;
  const int b = bh >> 4, h = bh & 15;
  const int q0 = qb * 64;
  const int lr = l & 15, lg = l >> 4;
  const float SC = 0.18033688011f;   // 0.125 * log2(e)

  bf16x8 qf[2];
  {
    const bf16* qp = qkv + (size_t)(b * TT + q0 + w * 16 + lr) * QKVN + h * HD + lg * 8;
    qf[0] = *(const bf16x8*)qp;
    qf[1] = *(const bf16x8*)(qp + 32);
  }

  f32x4 Oa[4] = {};
  float mrow[4], lrow[4];
#pragma unroll
  for (int j = 0; j < 4; j++) { mrow[j] = -1e30f; lrow[j] = 0.f; }

  int kb0 = qb - 2; if (kb0 < 0) kb0 = 0;
  int kb1 = qb + 2; if (kb1 > 31) kb1 = 31;

  for (int kb = kb0; kb <= kb1; ++kb) {
    const int kvbase = kb * 64;
#pragma unroll
    for (int task = 0; task < 2; task++) {
      int lin = tid + 256 * task;
      int r = lin >> 3, cb = lin & 7;
      const bf16* kp = qkv + (size_t)(b * TT + kvbase + r) * QKVN + DIMC + h * HD + cb * 8;
      *(bf16x8*)&Kl[r][cb * 8] = *(const bf16x8*)kp;
    }
#pragma unroll
    for (int task = 0; task < 2; task++) {
      int lin = tid + 256 * task;
      int r = lin & 63, c0 = (lin >> 6) * 8;
      bf16x8 vv = *(const bf16x8*)(qkv + (size_t)(b * TT + kvbase + r) * QKVN + 2 * DIMC + h * HD + c0);
#pragma unroll
      for (int e = 0; e < 8; e++) Vt[c0 + e][r] = vv[e];
    }
    __syncthreads();

    f32x4 Sa[4] = {};
#pragma unroll
    for (int kf = 0; kf < 2; kf++)
#pragma unroll
      for (int nf = 0; nf < 4; nf++) {
        bf16x8 kfr = *(const bf16x8*)&Kl[nf * 16 + lr][kf * 32 + lg * 8];
        Sa[nf] = __builtin_amdgcn_mfma_f32_16x16x32_bf16(qf[kf], kfr, Sa[nf], 0, 0, 0);
      }

    float mblk[4];
#pragma unroll
    for (int j = 0; j < 4; j++) mblk[j] = -1e30f;
    const int qrow_ = q0 + w * 16 + lg * 4;
#pragma unroll
    for (int nf = 0; nf < 4; nf++) {
      int kv = kvbase + nf * 16 + lr;
#pragma unroll
      for (int j = 0; j < 4; j++) {
        int dq = qrow_ + j - kv;
        float s = Sa[nf][j] * SC;
        if (dq > WINDOW || dq < -WINDOW) s = -1e30f;
        Sa[nf][j] = s;
        mblk[j] = fmaxf(mblk[j], s);
      }
    }
#pragma unroll
    for (int j = 0; j < 4; j++) {
#pragma unroll
      for (int sh = 1; sh < 16; sh <<= 1)
        mblk[j] = fmaxf(mblk[j], __shfl_xor(mblk[j], sh, 16));
    }
    float scl[4];
#pragma unroll
    for (int j = 0; j < 4; j++) {
      float mn = fmaxf(mrow[j], mblk[j]);
      scl[j] = exp2f(mrow[j] - mn);
      mrow[j] = mn;
    }
    float rsum[4] = {0.f, 0.f, 0.f, 0.f};
#pragma unroll
    for (int nf = 0; nf < 4; nf++)
#pragma unroll
      for (int j = 0; j < 4; j++) {
        float p = exp2f(Sa[nf][j] - mrow[j]);
        Sa[nf][j] = p;
        rsum[j] += p;
      }
#pragma unroll
    for (int j = 0; j < 4; j++) {
#pragma unroll
      for (int sh = 1; sh < 16; sh <<= 1)
        rsum[j] += __shfl_xor(rsum[j], sh, 16);
      lrow[j] = lrow[j] * scl[j] + rsum[j];
    }
#pragma unroll
    for (int nf = 0; nf < 4; nf++)
#pragma unroll
      for (int j = 0; j < 4; j++) Oa[nf][j] *= scl[j];

#pragma unroll
    for (int nf = 0; nf < 4; nf++)
#pragma unroll
      for (int j = 0; j < 4; j++)
        Pl[w][lg * 4 + j][nf * 16 + lr] = (bf16)Sa[nf][j];
#pragma unroll
    for (int kf = 0; kf < 2; kf++) {
      bf16x8 pf = *(const bf16x8*)&Pl[w][lr][kf * 32 + lg * 8];
#pragma unroll
      for (int nf = 0; nf < 4; nf++) {
        bf16x8 vfr = *(const bf16x8*)&Vt[nf * 16 + lr][kf * 32 + lg * 8];
        Oa[nf] = __builtin_amdgcn_mfma_f32_16x16x32_bf16(pf, vfr, Oa[nf], 0, 0, 0);
      }
    }
    __syncthreads();
  }

#pragma unroll
  for (int nf = 0; nf < 4; nf++) {
#pragma unroll
    for (int j = 0; j < 4; j++) {
      int qrow = q0 + w * 16 + lg * 4 + j;
      int d = nf * 16 + lr;
      out[(size_t)(b * TT + qrow) * DIMC + h * HD + d] = (bf16)(Oa[nf][j] / lrow[j]);
    }
  }
}

// ---------------------------------------------------------------- launch
extern "C" void kernel_launch(void* const* d_in, const int* in_sizes, int n_in,
                              void* d_out, int out_size, void* d_ws, size_t ws_size,
                              hipStream_t stream) {
  const float* x     = (const float*)d_in[0];
  const float* Wqkv  = (const float*)d_in[1];
  const float* Wproj = (const float*)d_in[2];
  const float* bproj = (const float*)d_in[3];
  float* out = (float*)d_out;

  char* ws = (char*)d_ws;
  bf16* xb   = (bf16*)(ws);
  bf16* wqb  = (bf16*)(ws + 8388608);
  bf16* wpb  = (bf16*)(ws + 14680064);
  bf16* qkvb = (bf16*)(ws + 16777216);
  bf16* aob  = (bf16*)(ws + 41943040);

  cast3_kernel<<<2048, 256, 0, stream>>>(x, Wqkv, Wproj, xb, wqb, wpb);
  gemm256_qkv_kernel<<<192, 512, 0, stream>>>(xb, wqb, qkvb);
  attn_kernel<<<1024, 256, 0, stream>>>(qkvb, aob);
  gemm_bt_kernel<DIMC><<<dim3(32 * 8), 256, 0, stream>>>(aob, wpb, out, bproj);
}

// Round 3
// 98.111 us; speedup vs baseline: 1.0413x; 1.0413x over previous
//
#include <hip/hip_runtime.h>
#include <hip/hip_bf16.h>
#include <cstdint>
#include <cstddef>

#define DIMC 1024
#define HEADS 16
#define HD 64
#define WINDOW 128
#define BB 2
#define TT 2048
#define NTOK (BB*TT)       // 4096
#define QKVN (3*DIMC)      // 3072

typedef __bf16 bf16;
typedef __bf16 bf16x8 __attribute__((ext_vector_type(8)));
typedef __bf16 bf16x4 __attribute__((ext_vector_type(4)));
typedef float f32x4 __attribute__((ext_vector_type(4)));
typedef unsigned int u32;

typedef const __attribute__((address_space(1))) u32* gp1_t;
typedef __attribute__((address_space(3))) u32* lp3_t;

__device__ __forceinline__ void gload16(const void* g, void* l) {
  __builtin_amdgcn_global_load_lds((gp1_t)g, (lp3_t)l, 16, 0, 0);
}

__device__ __forceinline__ void BAR() {
  asm volatile("" ::: "memory");
  __builtin_amdgcn_s_barrier();
  asm volatile("" ::: "memory");
}

// ---------------------------------------------------------------- cast kernel
__global__ void cast3_kernel(const float* __restrict__ x,
                             const float* __restrict__ wq,
                             const float* __restrict__ wp,
                             bf16* __restrict__ xo,
                             bf16* __restrict__ wqo,
                             bf16* __restrict__ wpo) {
  const int NX = NTOK * DIMC / 4;
  const int NQ = QKVN * DIMC / 4;
  const int NP = DIMC * DIMC / 4;
  const int total = NX + NQ + NP;
  typedef float float4v __attribute__((ext_vector_type(4)));
  for (int i = blockIdx.x * blockDim.x + threadIdx.x; i < total;
       i += gridDim.x * blockDim.x) {
    const float4v* src; bf16* dst; int j;
    if (i < NX)            { src = (const float4v*)x;  dst = xo;  j = i; }
    else if (i < NX + NQ)  { src = (const float4v*)wq; dst = wqo; j = i - NX; }
    else                   { src = (const float4v*)wp; dst = wpo; j = i - NX - NQ; }
    float4v v = src[j];
    bf16x4 o;
    o[0] = (bf16)v[0]; o[1] = (bf16)v[1]; o[2] = (bf16)v[2]; o[3] = (bf16)v[3];
    ((bf16x4*)dst)[j] = o;
  }
}

// ---------------------------------------------------------------- 256x256 GEMM (C = A * B^T, bf16 out)
// Swizzle: logical (row, colb[0..127]) stored at colb ^ ((row&7)<<4).
// Read slot = lg ^ (lr&7): 8 lanes per 16B slot, distinct rows -> conflict-free b128.
__device__ __forceinline__ bf16x8 lds_frag(const bf16* base, int row, int colb) {
  const char* p = (const char*)base + row * 128 + (colb ^ ((row & 7) << 4));
  return *(const bf16x8*)p;
}

__global__ __launch_bounds__(512, 2) void gemm256_qkv_kernel(
    const bf16* __restrict__ A, const bf16* __restrict__ Bw,
    bf16* __restrict__ C) {
  constexpr int K = 1024;
  constexpr int NT = K / 64;             // 16 K-tiles
  __shared__ bf16 Alds[2][256 * 64];
  __shared__ bf16 Blds[2][256 * 64];

  const int tid = threadIdx.x;
  const int wid = tid >> 6, l = tid & 63;
  const int wm = wid >> 2, wn = wid & 3;
  const int lr = l & 15, lg = l >> 4;
  const int w8 = wid * 8;

  const int bid = blockIdx.x;
  const int wg = (bid & 7) * 24 + (bid >> 3);   // 192 % 8 == 0, bijective
  const int bm = wg & 15;
  const int bn = wg >> 4;

  const char* Ag = (const char*)A + (size_t)(bm * 256) * 2048;
  const char* Bg = (const char*)Bw + (size_t)(bn * 256) * 2048;

  // stage one half-tile (128 rows x 64 cols). half0 = rows {0-63,128-191},
  // half1 = {64-127,192-255}. LDS dest linear; source col inverse-swizzled.
  auto stage = [&](bf16* lds, const char* gbase, int kt, int half) {
#pragma unroll
    for (int i = 0; i < 2; i++) {
      const int R0 = half * 64 + i * 128 + w8;
      const int r = R0 + (l >> 3);
      const char* src = gbase + (size_t)r * 2048 + kt * 128
                        + (((l & 7) * 16) ^ ((r & 7) << 4));
      gload16(src, lds + R0 * 64);
    }
  };

  // prologue: leaves [B0(k1),B1(k1),A0(k1)] = 6 in flight
  stage(Blds[0], Bg, 0, 0);
  stage(Blds[0], Bg, 0, 1);
  stage(Alds[0], Ag, 0, 0);
  stage(Alds[0], Ag, 0, 1);
  stage(Blds[1], Bg, 1, 0);
  stage(Blds[1], Bg, 1, 1);
  stage(Alds[1], Ag, 1, 0);
  asm volatile("s_waitcnt vmcnt(6)" ::: "memory");
  BAR();

  f32x4 acc[8][4] = {};

  // one K-tile: 4 phases; reads for phase p+1 issued before phase p's MFMA
  // (compiler inserts counted lgkmcnt). One barrier per phase.
  auto ktile = [&](int kt, const bf16* Acur, const bf16* Bcur,
                   bf16* Anext, bf16* Acur_w, bf16* Bcur_w) {
    bf16x8 bfr[4][2];
    bf16x8 afr[2][2], afn[2][2];
#pragma unroll
    for (int n = 0; n < 4; n++)
#pragma unroll
      for (int kk = 0; kk < 2; kk++)
        bfr[n][kk] = lds_frag(Bcur, wn * 64 + n * 16 + lr, kk * 64 + lg * 16);
#pragma unroll
    for (int mi = 0; mi < 2; mi++)
#pragma unroll
      for (int kk = 0; kk < 2; kk++)
        afr[mi][kk] = lds_frag(Acur, wm * 128 + mi * 16 + lr, kk * 64 + lg * 16);

#pragma unroll
    for (int mq = 0; mq < 4; ++mq) {
      if (mq < 3) {
#pragma unroll
        for (int mi = 0; mi < 2; mi++)
#pragma unroll
          for (int kk = 0; kk < 2; kk++)
            afn[mi][kk] = lds_frag(Acur, wm * 128 + (2 * (mq + 1) + mi) * 16 + lr,
                                   kk * 64 + lg * 16);
      }
      // staging: ph0: A-h1(kt+1); ph1: B-h0(kt+2); ph2: B-h1(kt+2); ph3: A-h0(kt+2)
      if (mq == 0)      { if (kt + 1 < NT) stage(Anext,  Ag, kt + 1, 1); }
      else if (mq == 1) { if (kt + 2 < NT) stage(Bcur_w, Bg, kt + 2, 0); }
      else if (mq == 2) { if (kt + 2 < NT) stage(Bcur_w, Bg, kt + 2, 1); }
      else              { if (kt + 2 < NT) stage(Acur_w, Ag, kt + 2, 0); }
      __builtin_amdgcn_s_setprio(1);
#pragma unroll
      for (int kk = 0; kk < 2; kk++)
#pragma unroll
        for (int mi = 0; mi < 2; mi++)
#pragma unroll
          for (int n = 0; n < 4; n++)
            acc[2 * mq + mi][n] = __builtin_amdgcn_mfma_f32_16x16x32_bf16(
                afr[mi][kk], bfr[n][kk], acc[2 * mq + mi][n], 0, 0, 0);
      __builtin_amdgcn_s_setprio(0);
      if (mq == 3) {
        if (kt == NT - 2) asm volatile("s_waitcnt vmcnt(0)" ::: "memory");
        else              asm volatile("s_waitcnt vmcnt(6)" ::: "memory");
      }
      BAR();
      if (mq < 3) {
#pragma unroll
        for (int mi = 0; mi < 2; mi++)
#pragma unroll
          for (int kk = 0; kk < 2; kk++)
            afr[mi][kk] = afn[mi][kk];
      }
    }
  };

  for (int kt2 = 0; kt2 < NT; kt2 += 2) {
    ktile(kt2,     Alds[0], Blds[0], Alds[1], Alds[0], Blds[0]);
    ktile(kt2 + 1, Alds[1], Blds[1], Alds[0], Alds[1], Blds[1]);
  }

#pragma unroll
  for (int m = 0; m < 8; m++) {
    const int row = bm * 256 + wm * 128 + m * 16 + lg * 4;
#pragma unroll
    for (int n = 0; n < 4; n++) {
      const int col = bn * 256 + wn * 64 + n * 16 + lr;
#pragma unroll
      for (int j = 0; j < 4; j++)
        C[(size_t)(row + j) * QKVN + col] = (bf16)acc[m][n][j];
    }
  }
}

// ---------------------------------------------------------------- 128x128 GEMM (proj, fp32 out + bias)
template<int N_>
__global__ __launch_bounds__(256, 2) void gemm_bt_kernel(
    const bf16* __restrict__ A, const bf16* __restrict__ Bw,
    float* __restrict__ Cf, const float* __restrict__ bias) {
  constexpr int K = 1024;
  constexpr int KB = K * 2;
  __shared__ bf16 As[2][128 * 32];
  __shared__ bf16 Bs[2][128 * 32];

  const int tid = threadIdx.x;
  const int w = tid >> 6, l = tid & 63;
  const int bm = blockIdx.x & 31;
  const int bn = blockIdx.x >> 5;
  const int wm = w >> 1, wn = w & 1;
  const int lr = l & 15, lg = l >> 4;

  const int srow = w * 32 + (l >> 2);
  const int scolb = (l & 3) * 16;
  const char* Agb = (const char*)A + (size_t)(bm * 128 + srow) * KB + scolb;
  const char* Bgb = (const char*)Bw + (size_t)(bn * 128 + srow) * KB + scolb;

  f32x4 acc[4][4] = {};

  auto stage = [&](int buf, int t) {
    const char* ag = Agb + t * 64;
    const char* bg = Bgb + t * 64;
    gload16(ag,            &As[buf][(w * 32) * 32]);
    gload16(ag + 16 * KB,  &As[buf][(w * 32 + 16) * 32]);
    gload16(bg,            &Bs[buf][(w * 32) * 32]);
    gload16(bg + 16 * KB,  &Bs[buf][(w * 32 + 16) * 32]);
  };

  stage(0, 0);
  __syncthreads();
  constexpr int NTiles = K / 32;
  int buf = 0;
  for (int t = 0; t < NTiles; ++t) {
    if (t + 1 < NTiles) stage(buf ^ 1, t + 1);
    bf16x8 af[4], bfr[4];
#pragma unroll
    for (int m = 0; m < 4; m++)
      af[m] = *(const bf16x8*)&As[buf][(wm * 64 + m * 16 + lr) * 32 + lg * 8];
#pragma unroll
    for (int n = 0; n < 4; n++)
      bfr[n] = *(const bf16x8*)&Bs[buf][(wn * 64 + n * 16 + lr) * 32 + lg * 8];
#pragma unroll
    for (int m = 0; m < 4; m++)
#pragma unroll
      for (int n = 0; n < 4; n++)
        acc[m][n] = __builtin_amdgcn_mfma_f32_16x16x32_bf16(af[m], bfr[n], acc[m][n], 0, 0, 0);
    __syncthreads();
    buf ^= 1;
  }

#pragma unroll
  for (int m = 0; m < 4; m++) {
    const int row = bm * 128 + wm * 64 + m * 16 + lg * 4;
#pragma unroll
    for (int n = 0; n < 4; n++) {
      const int col = bn * 128 + wn * 64 + n * 16 + lr;
#pragma unroll
      for (int j = 0; j < 4; j++)
        Cf[(size_t)(row + j) * N_ + col] = acc[m][n][j] + bias[col];
    }
  }
}

// ---------------------------------------------------------------- attention
__global__ __launch_bounds__(256, 2) void attn_kernel(const bf16* __restrict__ qkv,
                                                      bf16* __restrict__ out) {
  __shared__ bf16 Kl[64][72];
  __shared__ bf16 Vt[64][72];
  __shared__ bf16 Pl[4][16][72];

  const int tid = threadIdx.x, w = tid >> 6, l = tid & 63;
  const int qb = blockIdx.x & 31, bh = blockIdx.x >> 5;
  const int b = bh >> 4, h = bh & 15;
  const int q0 = qb * 64;
  const int lr = l & 15, lg = l >> 4;
  const float SC = 0.18033688011f;   // 0.125 * log2(e)

  bf16x8 qf[2];
  {
    const bf16* qp = qkv + (size_t)(b * TT + q0 + w * 16 + lr) * QKVN + h * HD + lg * 8;
    qf[0] = *(const bf16x8*)qp;
    qf[1] = *(const bf16x8*)(qp + 32);
  }

  f32x4 Oa[4] = {};
  float mrow[4], lrow[4];
#pragma unroll
  for (int j = 0; j < 4; j++) { mrow[j] = -1e30f; lrow[j] = 0.f; }

  int kb0 = qb - 2; if (kb0 < 0) kb0 = 0;
  int kb1 = qb + 2; if (kb1 > 31) kb1 = 31;

  for (int kb = kb0; kb <= kb1; ++kb) {
    const int kvbase = kb * 64;
#pragma unroll
    for (int task = 0; task < 2; task++) {
      int lin = tid + 256 * task;
      int r = lin >> 3, cb = lin & 7;
      const bf16* kp = qkv + (size_t)(b * TT + kvbase + r) * QKVN + DIMC + h * HD + cb * 8;
      *(bf16x8*)&Kl[r][cb * 8] = *(const bf16x8*)kp;
    }
#pragma unroll
    for (int task = 0; task < 2; task++) {
      int lin = tid + 256 * task;
      int r = lin & 63, c0 = (lin >> 6) * 8;
      bf16x8 vv = *(const bf16x8*)(qkv + (size_t)(b * TT + kvbase + r) * QKVN + 2 * DIMC + h * HD + c0);
#pragma unroll
      for (int e = 0; e < 8; e++) Vt[c0 + e][r] = vv[e];
    }
    __syncthreads();

    f32x4 Sa[4] = {};
#pragma unroll
    for (int kf = 0; kf < 2; kf++)
#pragma unroll
      for (int nf = 0; nf < 4; nf++) {
        bf16x8 kfr = *(const bf16x8*)&Kl[nf * 16 + lr][kf * 32 + lg * 8];
        Sa[nf] = __builtin_amdgcn_mfma_f32_16x16x32_bf16(qf[kf], kfr, Sa[nf], 0, 0, 0);
      }

    float mblk[4];
#pragma unroll
    for (int j = 0; j < 4; j++) mblk[j] = -1e30f;
    const int qrow_ = q0 + w * 16 + lg * 4;
#pragma unroll
    for (int nf = 0; nf < 4; nf++) {
      int kv = kvbase + nf * 16 + lr;
#pragma unroll
      for (int j = 0; j < 4; j++) {
        int dq = qrow_ + j - kv;
        float s = Sa[nf][j] * SC;
        if (dq > WINDOW || dq < -WINDOW) s = -1e30f;
        Sa[nf][j] = s;
        mblk[j] = fmaxf(mblk[j], s);
      }
    }
#pragma unroll
    for (int j = 0; j < 4; j++) {
#pragma unroll
      for (int sh = 1; sh < 16; sh <<= 1)
        mblk[j] = fmaxf(mblk[j], __shfl_xor(mblk[j], sh, 16));
    }
    float scl[4];
#pragma unroll
    for (int j = 0; j < 4; j++) {
      float mn = fmaxf(mrow[j], mblk[j]);
      scl[j] = exp2f(mrow[j] - mn);
      mrow[j] = mn;
    }
    float rsum[4] = {0.f, 0.f, 0.f, 0.f};
#pragma unroll
    for (int nf = 0; nf < 4; nf++)
#pragma unroll
      for (int j = 0; j < 4; j++) {
        float p = exp2f(Sa[nf][j] - mrow[j]);
        Sa[nf][j] = p;
        rsum[j] += p;
      }
#pragma unroll
    for (int j = 0; j < 4; j++) {
#pragma unroll
      for (int sh = 1; sh < 16; sh <<= 1)
        rsum[j] += __shfl_xor(rsum[j], sh, 16);
      lrow[j] = lrow[j] * scl[j] + rsum[j];
    }
#pragma unroll
    for (int nf = 0; nf < 4; nf++)
#pragma unroll
      for (int j = 0; j < 4; j++) Oa[nf][j] *= scl[j];

#pragma unroll
    for (int nf = 0; nf < 4; nf++)
#pragma unroll
      for (int j = 0; j < 4; j++)
        Pl[w][lg * 4 + j][nf * 16 + lr] = (bf16)Sa[nf][j];
#pragma unroll
    for (int kf = 0; kf < 2; kf++) {
      bf16x8 pf = *(const bf16x8*)&Pl[w][lr][kf * 32 + lg * 8];
#pragma unroll
      for (int nf = 0; nf < 4; nf++) {
        bf16x8 vfr = *(const bf16x8*)&Vt[nf * 16 + lr][kf * 32 + lg * 8];
        Oa[nf] = __builtin_amdgcn_mfma_f32_16x16x32_bf16(pf, vfr, Oa[nf], 0, 0, 0);
      }
    }
    __syncthreads();
  }

#pragma unroll
  for (int nf = 0; nf < 4; nf++) {
#pragma unroll
    for (int j = 0; j < 4; j++) {
      int qrow = q0 + w * 16 + lg * 4 + j;
      int d = nf * 16 + lr;
      out[(size_t)(b * TT + qrow) * DIMC + h * HD + d] = (bf16)(Oa[nf][j] / lrow[j]);
    }
  }
}

// ---------------------------------------------------------------- launch
extern "C" void kernel_launch(void* const* d_in, const int* in_sizes, int n_in,
                              void* d_out, int out_size, void* d_ws, size_t ws_size,
                              hipStream_t stream) {
  const float* x     = (const float*)d_in[0];
  const float* Wqkv  = (const float*)d_in[1];
  const float* Wproj = (const float*)d_in[2];
  const float* bproj = (const float*)d_in[3];
  float* out = (float*)d_out;

  char* ws = (char*)d_ws;
  bf16* xb   = (bf16*)(ws);
  bf16* wqb  = (bf16*)(ws + 8388608);
  bf16* wpb  = (bf16*)(ws + 14680064);
  bf16* qkvb = (bf16*)(ws + 16777216);
  bf16* aob  = (bf16*)(ws + 41943040);

  cast3_kernel<<<2048, 256, 0, stream>>>(x, Wqkv, Wproj, xb, wqb, wpb);
  gemm256_qkv_kernel<<<192, 512, 0, stream>>>(xb, wqb, qkvb);
  attn_kernel<<<1024, 256, 0, stream>>>(qkvb, aob);
  gemm_bt_kernel<DIMC><<<dim3(32 * 8), 256, 0, stream>>>(aob, wpb, out, bproj);
}

// Round 4
// 93.443 us; speedup vs baseline: 1.0933x; 1.0499x over previous
//
#include <hip/hip_runtime.h>
#include <hip/hip_bf16.h>
#include <cstdint>
#include <cstddef>

#define DIMC 1024
#define HEADS 16
#define HD 64
#define WINDOW 128
#define BB 2
#define TT 2048
#define NTOK (BB*TT)       // 4096
#define QKVN (3*DIMC)      // 3072

typedef __bf16 bf16;
typedef __bf16 bf16x8 __attribute__((ext_vector_type(8)));
typedef __bf16 bf16x4 __attribute__((ext_vector_type(4)));
typedef float f32x4 __attribute__((ext_vector_type(4)));
typedef unsigned int u32;

typedef const __attribute__((address_space(1))) u32* gp1_t;
typedef __attribute__((address_space(3))) u32* lp3_t;

__device__ __forceinline__ void gload16(const void* g, void* l) {
  __builtin_amdgcn_global_load_lds((gp1_t)g, (lp3_t)l, 16, 0, 0);
}

__device__ __forceinline__ void BAR() {
  asm volatile("" ::: "memory");
  __builtin_amdgcn_s_barrier();
  asm volatile("" ::: "memory");
}

// ---------------------------------------------------------------- cast kernel
__global__ void cast3_kernel(const float* __restrict__ x,
                             const float* __restrict__ wq,
                             const float* __restrict__ wp,
                             bf16* __restrict__ xo,
                             bf16* __restrict__ wqo,
                             bf16* __restrict__ wpo) {
  const int NX = NTOK * DIMC / 4;
  const int NQ = QKVN * DIMC / 4;
  const int NP = DIMC * DIMC / 4;
  const int total = NX + NQ + NP;
  typedef float float4v __attribute__((ext_vector_type(4)));
  for (int i = blockIdx.x * blockDim.x + threadIdx.x; i < total;
       i += gridDim.x * blockDim.x) {
    const float4v* src; bf16* dst; int j;
    if (i < NX)            { src = (const float4v*)x;  dst = xo;  j = i; }
    else if (i < NX + NQ)  { src = (const float4v*)wq; dst = wqo; j = i - NX; }
    else                   { src = (const float4v*)wp; dst = wpo; j = i - NX - NQ; }
    float4v v = src[j];
    bf16x4 o;
    o[0] = (bf16)v[0]; o[1] = (bf16)v[1]; o[2] = (bf16)v[2]; o[3] = (bf16)v[3];
    ((bf16x4*)dst)[j] = o;
  }
}

// ---------------------------------------------------------------- 256x192 GEMM (C = A * B^T, bf16 out)
// Swizzle: logical (row, colb[0..127]) stored at colb ^ ((row&7)<<4) -> b128
// reads are 2-way max (free), stage source inverse-swizzled (rule #21).
__device__ __forceinline__ bf16x8 lds_frag(const bf16* base, int row, int colb) {
  const char* p = (const char*)base + row * 128 + (colb ^ ((row & 7) << 4));
  return *(const bf16x8*)p;
}

__global__ __launch_bounds__(512, 2) void gemm256_qkv_kernel(
    const bf16* __restrict__ A, const bf16* __restrict__ Bw,
    bf16* __restrict__ C) {
  constexpr int K = 1024;
  constexpr int NT = K / 64;             // 16 K-tiles
  __shared__ bf16 Alds[2][256 * 64];     // 64 KB
  __shared__ bf16 Blds[2][192 * 64];     // 48 KB

  const int tid = threadIdx.x;
  const int wid = tid >> 6, l = tid & 63;
  const int wm = wid >> 2, wn = wid & 3;
  const int lr = l & 15, lg = l >> 4;
  const int w8 = wid * 8;

  const int bid = blockIdx.x;
  const int wg = (bid & 7) * 32 + (bid >> 3);   // 256 % 8 == 0, bijective
  const int bm = wg & 15;                // M/256 = 16
  const int bn = wg >> 4;                // N/192 = 16

  const char* Ag = (const char*)A + (size_t)(bm * 256) * 2048;
  const char* Bg = (const char*)Bw + (size_t)(bn * 192) * 2048;

  // A half-tile: half0 = rows {0-63,128-191} (= both waves' phases 0,1),
  // half1 = {64-127,192-255}. 2 gload16/wave.
  auto stageA = [&](bf16* lds, int kt, int half) {
#pragma unroll
    for (int i = 0; i < 2; i++) {
      const int R0 = half * 64 + i * 128 + w8;
      const int r = R0 + (l >> 3);
      const char* src = Ag + (size_t)r * 2048 + kt * 128
                        + (((l & 7) * 16) ^ ((r & 7) << 4));
      gload16(src, lds + R0 * 64);
    }
  };
  // B third-tile: 64 rows, 1 gload16/wave.
  auto stageB = [&](bf16* lds, int kt, int third) {
    const int R0 = third * 64 + w8;
    const int r = R0 + (l >> 3);
    const char* src = Bg + (size_t)r * 2048 + kt * 128
                      + (((l & 7) * 16) ^ ((r & 7) << 4));
    gload16(src, lds + R0 * 64);
  };

  // prologue: kt0 full (7 loads) + kt1 B(3) + kt1 A-h0(2) = 12 loads.
  // entering ktile(0) needs the first 7 complete -> vmcnt(5).
  stageB(Blds[0], 0, 0); stageB(Blds[0], 0, 1); stageB(Blds[0], 0, 2);
  stageA(Alds[0], 0, 0); stageA(Alds[0], 0, 1);
  stageB(Blds[1], 1, 0); stageB(Blds[1], 1, 1); stageB(Blds[1], 1, 2);
  stageA(Alds[1], 1, 0);
  asm volatile("s_waitcnt vmcnt(5)" ::: "memory");
  BAR();

  f32x4 acc[8][3] = {};

  // K-tile: 4 phases; A-frags for phase p+1 prefetched during p;
  // stage issue order per tile: ph0 A-h1(kt+1)[2], ph1 B-t0(kt+2)[1],
  // ph2 B-t1,t2(kt+2)[2], ph3 A-h0(kt+2)[2] -> steady vmcnt(5) at ph3.
  auto ktile = [&](int kt, const bf16* Acur, const bf16* Bcur,
                   bf16* Anext, bf16* Acur_w, bf16* Bcur_w) {
    bf16x8 bfr[3][2];
    bf16x8 afr[2][2], afn[2][2];
#pragma unroll
    for (int n = 0; n < 3; n++)
#pragma unroll
      for (int kk = 0; kk < 2; kk++)
        bfr[n][kk] = lds_frag(Bcur, wn * 48 + n * 16 + lr, kk * 64 + lg * 16);
#pragma unroll
    for (int mi = 0; mi < 2; mi++)
#pragma unroll
      for (int kk = 0; kk < 2; kk++)
        afr[mi][kk] = lds_frag(Acur, wm * 128 + mi * 16 + lr, kk * 64 + lg * 16);

#pragma unroll
    for (int mq = 0; mq < 4; ++mq) {
      if (mq < 3) {
#pragma unroll
        for (int mi = 0; mi < 2; mi++)
#pragma unroll
          for (int kk = 0; kk < 2; kk++)
            afn[mi][kk] = lds_frag(Acur, wm * 128 + (2 * (mq + 1) + mi) * 16 + lr,
                                   kk * 64 + lg * 16);
      }
      if (mq == 0)      { if (kt + 1 < NT) stageA(Anext,  kt + 1, 1); }
      else if (mq == 1) { if (kt + 2 < NT) stageB(Bcur_w, kt + 2, 0); }
      else if (mq == 2) { if (kt + 2 < NT) { stageB(Bcur_w, kt + 2, 1);
                                             stageB(Bcur_w, kt + 2, 2); } }
      else              { if (kt + 2 < NT) stageA(Acur_w, kt + 2, 0); }
      __builtin_amdgcn_s_setprio(1);
#pragma unroll
      for (int kk = 0; kk < 2; kk++)
#pragma unroll
        for (int mi = 0; mi < 2; mi++)
#pragma unroll
          for (int n = 0; n < 3; n++)
            acc[2 * mq + mi][n] = __builtin_amdgcn_mfma_f32_16x16x32_bf16(
                afr[mi][kk], bfr[n][kk], acc[2 * mq + mi][n], 0, 0, 0);
      __builtin_amdgcn_s_setprio(0);
      if (mq == 3) {
        if (kt >= NT - 2) asm volatile("s_waitcnt vmcnt(0)" ::: "memory");
        else              asm volatile("s_waitcnt vmcnt(5)" ::: "memory");
      }
      BAR();
      if (mq < 3) {
#pragma unroll
        for (int mi = 0; mi < 2; mi++)
#pragma unroll
          for (int kk = 0; kk < 2; kk++)
            afr[mi][kk] = afn[mi][kk];
      }
    }
  };

  for (int kt2 = 0; kt2 < NT; kt2 += 2) {
    ktile(kt2,     Alds[0], Blds[0], Alds[1], Alds[0], Blds[0]);
    ktile(kt2 + 1, Alds[1], Blds[1], Alds[0], Alds[1], Blds[1]);
  }

#pragma unroll
  for (int m = 0; m < 8; m++) {
    const int row = bm * 256 + wm * 128 + m * 16 + lg * 4;
#pragma unroll
    for (int n = 0; n < 3; n++) {
      const int col = bn * 192 + wn * 48 + n * 16 + lr;
#pragma unroll
      for (int j = 0; j < 4; j++)
        C[(size_t)(row + j) * QKVN + col] = (bf16)acc[m][n][j];
    }
  }
}

// ---------------------------------------------------------------- 128x128 GEMM (proj, fp32 out + bias)
template<int N_>
__global__ __launch_bounds__(256, 2) void gemm_bt_kernel(
    const bf16* __restrict__ A, const bf16* __restrict__ Bw,
    float* __restrict__ Cf, const float* __restrict__ bias) {
  constexpr int K = 1024;
  constexpr int KB = K * 2;
  __shared__ bf16 As[2][128 * 32];
  __shared__ bf16 Bs[2][128 * 32];

  const int tid = threadIdx.x;
  const int w = tid >> 6, l = tid & 63;
  const int bm = blockIdx.x & 31;
  const int bn = blockIdx.x >> 5;
  const int wm = w >> 1, wn = w & 1;
  const int lr = l & 15, lg = l >> 4;

  const int srow = w * 32 + (l >> 2);
  const int scolb = (l & 3) * 16;
  const char* Agb = (const char*)A + (size_t)(bm * 128 + srow) * KB + scolb;
  const char* Bgb = (const char*)Bw + (size_t)(bn * 128 + srow) * KB + scolb;

  f32x4 acc[4][4] = {};

  auto stage = [&](int buf, int t) {
    const char* ag = Agb + t * 64;
    const char* bg = Bgb + t * 64;
    gload16(ag,            &As[buf][(w * 32) * 32]);
    gload16(ag + 16 * KB,  &As[buf][(w * 32 + 16) * 32]);
    gload16(bg,            &Bs[buf][(w * 32) * 32]);
    gload16(bg + 16 * KB,  &Bs[buf][(w * 32 + 16) * 32]);
  };

  stage(0, 0);
  __syncthreads();
  constexpr int NTiles = K / 32;
  int buf = 0;
  for (int t = 0; t < NTiles; ++t) {
    if (t + 1 < NTiles) stage(buf ^ 1, t + 1);
    bf16x8 af[4], bfr[4];
#pragma unroll
    for (int m = 0; m < 4; m++)
      af[m] = *(const bf16x8*)&As[buf][(wm * 64 + m * 16 + lr) * 32 + lg * 8];
#pragma unroll
    for (int n = 0; n < 4; n++)
      bfr[n] = *(const bf16x8*)&Bs[buf][(wn * 64 + n * 16 + lr) * 32 + lg * 8];
#pragma unroll
    for (int m = 0; m < 4; m++)
#pragma unroll
      for (int n = 0; n < 4; n++)
        acc[m][n] = __builtin_amdgcn_mfma_f32_16x16x32_bf16(af[m], bfr[n], acc[m][n], 0, 0, 0);
    __syncthreads();
    buf ^= 1;
  }

#pragma unroll
  for (int m = 0; m < 4; m++) {
    const int row = bm * 128 + wm * 64 + m * 16 + lg * 4;
#pragma unroll
    for (int n = 0; n < 4; n++) {
      const int col = bn * 128 + wn * 64 + n * 16 + lr;
#pragma unroll
      for (int j = 0; j < 4; j++)
        Cf[(size_t)(row + j) * N_ + col] = acc[m][n][j] + bias[col];
    }
  }
}

// ---------------------------------------------------------------- attention
__global__ __launch_bounds__(256, 2) void attn_kernel(const bf16* __restrict__ qkv,
                                                      bf16* __restrict__ out) {
  __shared__ bf16 Kl[64][72];
  __shared__ bf16 Vt[64][72];
  __shared__ bf16 Pl[4][16][72];

  const int tid = threadIdx.x, w = tid >> 6, l = tid & 63;
  const int qb = blockIdx.x & 31, bh = blockIdx.x >> 5;
  const int b = bh >> 4, h = bh & 15;
  const int q0 = qb * 64;
  const int lr = l & 15, lg = l >> 4;
  const float SC = 0.18033688011f;   // 0.125 * log2(e)

  bf16x8 qf[2];
  {
    const bf16* qp = qkv + (size_t)(b * TT + q0 + w * 16 + lr) * QKVN + h * HD + lg * 8;
    qf[0] = *(const bf16x8*)qp;
    qf[1] = *(const bf16x8*)(qp + 32);
  }

  f32x4 Oa[4] = {};
  float mrow[4], lrow[4];
#pragma unroll
  for (int j = 0; j < 4; j++) { mrow[j] = -1e30f; lrow[j] = 0.f; }

  int kb0 = qb - 2; if (kb0 < 0) kb0 = 0;
  int kb1 = qb + 2; if (kb1 > 31) kb1 = 31;

  for (int kb = kb0; kb <= kb1; ++kb) {
    const int kvbase = kb * 64;
#pragma unroll
    for (int task = 0; task < 2; task++) {
      int lin = tid + 256 * task;
      int r = lin >> 3, cb = lin & 7;
      const bf16* kp = qkv + (size_t)(b * TT + kvbase + r) * QKVN + DIMC + h * HD + cb * 8;
      *(bf16x8*)&Kl[r][cb * 8] = *(const bf16x8*)kp;
    }
#pragma unroll
    for (int task = 0; task < 2; task++) {
      int lin = tid + 256 * task;
      int r = lin & 63, c0 = (lin >> 6) * 8;
      bf16x8 vv = *(const bf16x8*)(qkv + (size_t)(b * TT + kvbase + r) * QKVN + 2 * DIMC + h * HD + c0);
#pragma unroll
      for (int e = 0; e < 8; e++) Vt[c0 + e][r] = vv[e];
    }
    __syncthreads();

    f32x4 Sa[4] = {};
#pragma unroll
    for (int kf = 0; kf < 2; kf++)
#pragma unroll
      for (int nf = 0; nf < 4; nf++) {
        bf16x8 kfr = *(const bf16x8*)&Kl[nf * 16 + lr][kf * 32 + lg * 8];
        Sa[nf] = __builtin_amdgcn_mfma_f32_16x16x32_bf16(qf[kf], kfr, Sa[nf], 0, 0, 0);
      }

    float mblk[4];
#pragma unroll
    for (int j = 0; j < 4; j++) mblk[j] = -1e30f;
    const int qrow_ = q0 + w * 16 + lg * 4;
#pragma unroll
    for (int nf = 0; nf < 4; nf++) {
      int kv = kvbase + nf * 16 + lr;
#pragma unroll
      for (int j = 0; j < 4; j++) {
        int dq = qrow_ + j - kv;
        float s = Sa[nf][j] * SC;
        if (dq > WINDOW || dq < -WINDOW) s = -1e30f;
        Sa[nf][j] = s;
        mblk[j] = fmaxf(mblk[j], s);
      }
    }
#pragma unroll
    for (int j = 0; j < 4; j++) {
#pragma unroll
      for (int sh = 1; sh < 16; sh <<= 1)
        mblk[j] = fmaxf(mblk[j], __shfl_xor(mblk[j], sh, 16));
    }
    float scl[4];
#pragma unroll
    for (int j = 0; j < 4; j++) {
      float mn = fmaxf(mrow[j], mblk[j]);
      scl[j] = exp2f(mrow[j] - mn);
      mrow[j] = mn;
    }
    float rsum[4] = {0.f, 0.f, 0.f, 0.f};
#pragma unroll
    for (int nf = 0; nf < 4; nf++)
#pragma unroll
      for (int j = 0; j < 4; j++) {
        float p = exp2f(Sa[nf][j] - mrow[j]);
        Sa[nf][j] = p;
        rsum[j] += p;
      }
#pragma unroll
    for (int j = 0; j < 4; j++) {
#pragma unroll
      for (int sh = 1; sh < 16; sh <<= 1)
        rsum[j] += __shfl_xor(rsum[j], sh, 16);
      lrow[j] = lrow[j] * scl[j] + rsum[j];
    }
#pragma unroll
    for (int nf = 0; nf < 4; nf++)
#pragma unroll
      for (int j = 0; j < 4; j++) Oa[nf][j] *= scl[j];

#pragma unroll
    for (int nf = 0; nf < 4; nf++)
#pragma unroll
      for (int j = 0; j < 4; j++)
        Pl[w][lg * 4 + j][nf * 16 + lr] = (bf16)Sa[nf][j];
#pragma unroll
    for (int kf = 0; kf < 2; kf++) {
      bf16x8 pf = *(const bf16x8*)&Pl[w][lr][kf * 32 + lg * 8];
#pragma unroll
      for (int nf = 0; nf < 4; nf++) {
        bf16x8 vfr = *(const bf16x8*)&Vt[nf * 16 + lr][kf * 32 + lg * 8];
        Oa[nf] = __builtin_amdgcn_mfma_f32_16x16x32_bf16(pf, vfr, Oa[nf], 0, 0, 0);
      }
    }
    __syncthreads();
  }

#pragma unroll
  for (int nf = 0; nf < 4; nf++) {
#pragma unroll
    for (int j = 0; j < 4; j++) {
      int qrow = q0 + w * 16 + lg * 4 + j;
      int d = nf * 16 + lr;
      out[(size_t)(b * TT + qrow) * DIMC + h * HD + d] = (bf16)(Oa[nf][j] / lrow[j]);
    }
  }
}

// ---------------------------------------------------------------- launch
extern "C" void kernel_launch(void* const* d_in, const int* in_sizes, int n_in,
                              void* d_out, int out_size, void* d_ws, size_t ws_size,
                              hipStream_t stream) {
  const float* x     = (const float*)d_in[0];
  const float* Wqkv  = (const float*)d_in[1];
  const float* Wproj = (const float*)d_in[2];
  const float* bproj = (const float*)d_in[3];
  float* out = (float*)d_out;

  char* ws = (char*)d_ws;
  bf16* xb   = (bf16*)(ws);
  bf16* wqb  = (bf16*)(ws + 8388608);
  bf16* wpb  = (bf16*)(ws + 14680064);
  bf16* qkvb = (bf16*)(ws + 16777216);
  bf16* aob  = (bf16*)(ws + 41943040);

  cast3_kernel<<<2048, 256, 0, stream>>>(x, Wqkv, Wproj, xb, wqb, wpb);
  gemm256_qkv_kernel<<<256, 512, 0, stream>>>(xb, wqb, qkvb);
  attn_kernel<<<1024, 256, 0, stream>>>(qkvb, aob);
  gemm_bt_kernel<DIMC><<<dim3(32 * 8), 256, 0, stream>>>(aob, wpb, out, bproj);
}

// Round 5
// 89.442 us; speedup vs baseline: 1.1422x; 1.0447x over previous
//
#include <hip/hip_runtime.h>
#include <hip/hip_bf16.h>
#include <cstdint>
#include <cstddef>

#define DIMC 1024
#define HEADS 16
#define HD 64
#define WINDOW 128
#define BB 2
#define TT 2048
#define NTOK (BB*TT)       // 4096
#define QKVN (3*DIMC)      // 3072

typedef __bf16 bf16;
typedef __bf16 bf16x8 __attribute__((ext_vector_type(8)));
typedef __bf16 bf16x4 __attribute__((ext_vector_type(4)));
typedef float f32x4 __attribute__((ext_vector_type(4)));
typedef unsigned int u32;

typedef const __attribute__((address_space(1))) u32* gp1_t;
typedef __attribute__((address_space(3))) u32* lp3_t;

__device__ __forceinline__ void gload16(const void* g, void* l) {
  __builtin_amdgcn_global_load_lds((gp1_t)g, (lp3_t)l, 16, 0, 0);
}

__device__ __forceinline__ u32 lds_u32(const void* p) {
  return (u32)(uintptr_t)(__attribute__((address_space(3))) const void*)p;
}

__device__ __forceinline__ void BAR() {
  asm volatile("" ::: "memory");
  __builtin_amdgcn_s_barrier();
  asm volatile("" ::: "memory");
}

// ---------------------------------------------------------------- cast kernel
__global__ void cast3_kernel(const float* __restrict__ x,
                             const float* __restrict__ wq,
                             const float* __restrict__ wp,
                             bf16* __restrict__ xo,
                             bf16* __restrict__ wqo,
                             bf16* __restrict__ wpo) {
  const int NX = NTOK * DIMC / 4;
  const int NQ = QKVN * DIMC / 4;
  const int NP = DIMC * DIMC / 4;
  const int total = NX + NQ + NP;
  typedef float float4v __attribute__((ext_vector_type(4)));
  for (int i = blockIdx.x * blockDim.x + threadIdx.x; i < total;
       i += gridDim.x * blockDim.x) {
    const float4v* src; bf16* dst; int j;
    if (i < NX)            { src = (const float4v*)x;  dst = xo;  j = i; }
    else if (i < NX + NQ)  { src = (const float4v*)wq; dst = wqo; j = i - NX; }
    else                   { src = (const float4v*)wp; dst = wpo; j = i - NX - NQ; }
    float4v v = src[j];
    bf16x4 o;
    o[0] = (bf16)v[0]; o[1] = (bf16)v[1]; o[2] = (bf16)v[2]; o[3] = (bf16)v[3];
    ((bf16x4*)dst)[j] = o;
  }
}

// ---------------------------------------------------------------- 256x192 GEMM (C = A * B^T, bf16 out)
__device__ __forceinline__ bf16x8 lds_frag(const bf16* base, int row, int colb) {
  const char* p = (const char*)base + row * 128 + (colb ^ ((row & 7) << 4));
  return *(const bf16x8*)p;
}

__global__ __launch_bounds__(512, 2) void gemm256_qkv_kernel(
    const bf16* __restrict__ A, const bf16* __restrict__ Bw,
    bf16* __restrict__ C) {
  constexpr int K = 1024;
  constexpr int NT = K / 64;             // 16 K-tiles
  __shared__ bf16 Alds[2][256 * 64];
  __shared__ bf16 Blds[2][192 * 64];

  const int tid = threadIdx.x;
  const int wid = tid >> 6, l = tid & 63;
  const int wm = wid >> 2, wn = wid & 3;
  const int lr = l & 15, lg = l >> 4;
  const int w8 = wid * 8;

  const int bid = blockIdx.x;
  const int wg = (bid & 7) * 32 + (bid >> 3);   // 256 % 8 == 0, bijective
  const int bm = wg & 15;
  const int bn = wg >> 4;

  const char* Ag = (const char*)A + (size_t)(bm * 256) * 2048;
  const char* Bg = (const char*)Bw + (size_t)(bn * 192) * 2048;

  auto stageA = [&](bf16* lds, int kt, int half) {
#pragma unroll
    for (int i = 0; i < 2; i++) {
      const int R0 = half * 64 + i * 128 + w8;
      const int r = R0 + (l >> 3);
      const char* src = Ag + (size_t)r * 2048 + kt * 128
                        + (((l & 7) * 16) ^ ((r & 7) << 4));
      gload16(src, lds + R0 * 64);
    }
  };
  auto stageB = [&](bf16* lds, int kt, int third) {
    const int R0 = third * 64 + w8;
    const int r = R0 + (l >> 3);
    const char* src = Bg + (size_t)r * 2048 + kt * 128
                      + (((l & 7) * 16) ^ ((r & 7) << 4));
    gload16(src, lds + R0 * 64);
  };

  stageB(Blds[0], 0, 0); stageB(Blds[0], 0, 1); stageB(Blds[0], 0, 2);
  stageA(Alds[0], 0, 0); stageA(Alds[0], 0, 1);
  stageB(Blds[1], 1, 0); stageB(Blds[1], 1, 1); stageB(Blds[1], 1, 2);
  stageA(Alds[1], 1, 0);
  asm volatile("s_waitcnt vmcnt(5)" ::: "memory");
  BAR();

  f32x4 acc[8][3] = {};

  // two-barrier 8-phase template: [reads+stage] BAR lgkm(0) [MFMA] [vmcnt] BAR
  auto ktile = [&](int kt, const bf16* Acur, const bf16* Bcur,
                   bf16* Anext, bf16* Acur_w, bf16* Bcur_w) {
    bf16x8 bfr[3][2];
#pragma unroll
    for (int mq = 0; mq < 4; ++mq) {
      bf16x8 afr[2][2];
      if (mq == 0) {
#pragma unroll
        for (int n = 0; n < 3; n++)
#pragma unroll
          for (int kk = 0; kk < 2; kk++)
            bfr[n][kk] = lds_frag(Bcur, wn * 48 + n * 16 + lr, kk * 64 + lg * 16);
      }
#pragma unroll
      for (int mi = 0; mi < 2; mi++)
#pragma unroll
        for (int kk = 0; kk < 2; kk++)
          afr[mi][kk] = lds_frag(Acur, wm * 128 + (2 * mq + mi) * 16 + lr,
                                 kk * 64 + lg * 16);
      if (mq == 0)      { if (kt + 1 < NT) stageA(Anext,  kt + 1, 1); }
      else if (mq == 1) { if (kt + 2 < NT) stageB(Bcur_w, kt + 2, 0); }
      else if (mq == 2) { if (kt + 2 < NT) { stageB(Bcur_w, kt + 2, 1);
                                             stageB(Bcur_w, kt + 2, 2); } }
      else              { if (kt + 2 < NT) stageA(Acur_w, kt + 2, 0); }
      BAR();
      asm volatile("s_waitcnt lgkmcnt(0)" ::: "memory");
      __builtin_amdgcn_s_setprio(1);
#pragma unroll
      for (int kk = 0; kk < 2; kk++)
#pragma unroll
        for (int mi = 0; mi < 2; mi++)
#pragma unroll
          for (int n = 0; n < 3; n++)
            acc[2 * mq + mi][n] = __builtin_amdgcn_mfma_f32_16x16x32_bf16(
                afr[mi][kk], bfr[n][kk], acc[2 * mq + mi][n], 0, 0, 0);
      __builtin_amdgcn_s_setprio(0);
      if (mq == 3) {
        if (kt >= NT - 2) asm volatile("s_waitcnt vmcnt(0)" ::: "memory");
        else              asm volatile("s_waitcnt vmcnt(5)" ::: "memory");
      }
      BAR();
    }
  };

  for (int kt2 = 0; kt2 < NT; kt2 += 2) {
    ktile(kt2,     Alds[0], Blds[0], Alds[1], Alds[0], Blds[0]);
    ktile(kt2 + 1, Alds[1], Blds[1], Alds[0], Alds[1], Blds[1]);
  }

#pragma unroll
  for (int m = 0; m < 8; m++) {
    const int row = bm * 256 + wm * 128 + m * 16 + lg * 4;
#pragma unroll
    for (int n = 0; n < 3; n++) {
      const int col = bn * 192 + wn * 48 + n * 16 + lr;
#pragma unroll
      for (int j = 0; j < 4; j++)
        C[(size_t)(row + j) * QKVN + col] = (bf16)acc[m][n][j];
    }
  }
}

// ---------------------------------------------------------------- 128x128 GEMM (proj, fp32 out + bias)
template<int N_>
__global__ __launch_bounds__(256, 2) void gemm_bt_kernel(
    const bf16* __restrict__ A, const bf16* __restrict__ Bw,
    float* __restrict__ Cf, const float* __restrict__ bias) {
  constexpr int K = 1024;
  constexpr int KB = K * 2;
  __shared__ bf16 As[2][128 * 32];
  __shared__ bf16 Bs[2][128 * 32];

  const int tid = threadIdx.x;
  const int w = tid >> 6, l = tid & 63;
  const int bm = blockIdx.x & 31;
  const int bn = blockIdx.x >> 5;
  const int wm = w >> 1, wn = w & 1;
  const int lr = l & 15, lg = l >> 4;

  const int srow = w * 32 + (l >> 2);
  const int scolb = (l & 3) * 16;
  const char* Agb = (const char*)A + (size_t)(bm * 128 + srow) * KB + scolb;
  const char* Bgb = (const char*)Bw + (size_t)(bn * 128 + srow) * KB + scolb;

  f32x4 acc[4][4] = {};

  auto stage = [&](int buf, int t) {
    const char* ag = Agb + t * 64;
    const char* bg = Bgb + t * 64;
    gload16(ag,            &As[buf][(w * 32) * 32]);
    gload16(ag + 16 * KB,  &As[buf][(w * 32 + 16) * 32]);
    gload16(bg,            &Bs[buf][(w * 32) * 32]);
    gload16(bg + 16 * KB,  &Bs[buf][(w * 32 + 16) * 32]);
  };

  stage(0, 0);
  __syncthreads();
  constexpr int NTiles = K / 32;
  int buf = 0;
  for (int t = 0; t < NTiles; ++t) {
    if (t + 1 < NTiles) stage(buf ^ 1, t + 1);
    bf16x8 af[4], bfr[4];
#pragma unroll
    for (int m = 0; m < 4; m++)
      af[m] = *(const bf16x8*)&As[buf][(wm * 64 + m * 16 + lr) * 32 + lg * 8];
#pragma unroll
    for (int n = 0; n < 4; n++)
      bfr[n] = *(const bf16x8*)&Bs[buf][(wn * 64 + n * 16 + lr) * 32 + lg * 8];
#pragma unroll
    for (int m = 0; m < 4; m++)
#pragma unroll
      for (int n = 0; n < 4; n++)
        acc[m][n] = __builtin_amdgcn_mfma_f32_16x16x32_bf16(af[m], bfr[n], acc[m][n], 0, 0, 0);
    __syncthreads();
    buf ^= 1;
  }

#pragma unroll
  for (int m = 0; m < 4; m++) {
    const int row = bm * 128 + wm * 64 + m * 16 + lg * 4;
#pragma unroll
    for (int n = 0; n < 4; n++) {
      const int col = bn * 128 + wn * 64 + n * 16 + lr;
#pragma unroll
      for (int j = 0; j < 4; j++)
        Cf[(size_t)(row + j) * N_ + col] = acc[m][n][j] + bias[col];
    }
  }
}

// ---------------------------------------------------------------- attention v2
// Swapped-operand flash attn: S^T = mfma(K, Q); P stays in registers with the
// kv-permutation (4*lg+j) that pairs with ds_read_b64_tr_b16 of subtiled V.
// K staged swizzled via global_load_lds; V staged subtiled [td][tk][4][16].
__global__ __launch_bounds__(256, 4) void attn_kernel(const bf16* __restrict__ qkv,
                                                      bf16* __restrict__ out) {
  __shared__ bf16 Kl[2][64 * 64];   // swizzled rows of 128B
  __shared__ bf16 Vl[2][64 * 64];   // subtiled tiles of 4x16

  const int tid = threadIdx.x, w = tid >> 6, l = tid & 63;
  const int qb = blockIdx.x & 31, bh = blockIdx.x >> 5;
  const int b = bh >> 4, h = bh & 15;
  const int q0 = qb * 64;
  const int lr = l & 15, lg = l >> 4;
  const float SC = 0.18033688011f;   // 0.125 * log2(e)

  const char* qkv_b = (const char*)qkv + (size_t)(b * TT) * (QKVN * 2);

  // ---- per-lane staging source offsets (relative to kv row 0 of this batch)
  // K: 2 issues/wave, rows R0k = 8*(w+4i), lane covers row R0k + (l>>3),
  //    swizzled col; dest linear.
  size_t koff[2]; u32 kdst[2];
#pragma unroll
  for (int i = 0; i < 2; i++) {
    const int R0 = 8 * (w + 4 * i);
    const int r = R0 + (l >> 3);
    const int colb = (((l & 7) * 16) ^ (((l >> 3) & 7) << 4));
    koff[i] = (size_t)r * (QKVN * 2) + (DIMC + h * HD) * 2 + colb;
    kdst[i] = (u32)(R0 * 64);        // bf16 elements
  }
  // V: 2 issues/wave; chunk c = tid + 256*i; tile t=c>>3 (t = td*16+tk), w_=c&7
  //    -> kv = (t&15)*4 + (w_>>1), d = (t>>4)*16 + (w_&1)*8
  size_t voff[2]; u32 vdst[2];
#pragma unroll
  for (int i = 0; i < 2; i++) {
    const int c = tid + 256 * i;
    const int t = c >> 3, w_ = c & 7;
    const int kv = (t & 15) * 4 + (w_ >> 1);
    const int d  = (t >> 4) * 16 + (w_ & 1) * 8;
    voff[i] = (size_t)kv * (QKVN * 2) + (2 * DIMC + h * HD + d) * 2;
    vdst[i] = (u32)((w + 4 * i) * 512);  // bf16 elements (wave-uniform base part)
  }

  auto stage = [&](int buf, int kb) {
    const char* rowb = qkv_b + (size_t)(kb * 64) * (QKVN * 2);
#pragma unroll
    for (int i = 0; i < 2; i++)
      gload16(rowb + koff[i], &Kl[buf][kdst[i]]);
#pragma unroll
    for (int i = 0; i < 2; i++)
      gload16(rowb + voff[i], &Vl[buf][vdst[i]]);
  };

  // ---- Q fragments (B-operand): lane lr = q row, slots = d
  bf16x8 qf[2];
  {
    const bf16* qp = qkv + (size_t)(b * TT + q0 + w * 16 + lr) * QKVN + h * HD + lg * 8;
    qf[0] = *(const bf16x8*)qp;
    qf[1] = *(const bf16x8*)(qp + 32);
  }

  f32x4 Oa[4] = {};
  float mrow = -1e30f, lrow = 0.f;   // per-lane state for q = q0 + w*16 + lr

  int kb0 = qb - 2; if (kb0 < 0) kb0 = 0;
  int kb1 = qb + 2; if (kb1 > 31) kb1 = 31;

  stage(0, kb0);
  asm volatile("s_waitcnt vmcnt(0)" ::: "memory");
  BAR();

  for (int kb = kb0; kb <= kb1; ++kb) {
    const int c = (kb - kb0) & 1;
    if (kb + 1 <= kb1) stage(c ^ 1, kb + 1);

    // ---- S^T = mfma(K, Q): Sa[nf] lane reg j = S[kv=kb*64+nf*16+lg*4+j][q=lr]
    const bf16* Kb = &Kl[c][0];
    f32x4 Sa[4] = {};
#pragma unroll
    for (int kf = 0; kf < 2; kf++)
#pragma unroll
      for (int nf = 0; nf < 4; nf++) {
        const char* kp = (const char*)Kb + (nf * 16 + lr) * 128
                         + ((kf * 64 + lg * 16) ^ ((lr & 7) << 4));
        bf16x8 kfr = *(const bf16x8*)kp;
        Sa[nf] = __builtin_amdgcn_mfma_f32_16x16x32_bf16(kfr, qf[kf], Sa[nf], 0, 0, 0);
      }

    // ---- issue V transpose-reads early (hide under softmax VALU)
    bf16x4 tr0[4][2], tr1[4][2];
    {
      const u32 vbase = lds_u32(&Vl[c][0]) + l * 8;
#pragma unroll
      for (int nf = 0; nf < 4; nf++)
#pragma unroll
        for (int kf = 0; kf < 2; kf++) {
          const u32 a = vbase + (u32)((nf * 16 + kf * 8) * 128);
          asm volatile("ds_read_b64_tr_b16 %0, %1"
                       : "=v"(tr0[nf][kf]) : "v"(a));
          asm volatile("ds_read_b64_tr_b16 %0, %1 offset:512"
                       : "=v"(tr1[nf][kf]) : "v"(a));
        }
    }

    // ---- mask + scale + row(q)-max  (q = lr; kv = nf*16+lg*4+j)
    const int qrow = q0 + w * 16 + lr;
    const int kvb = kb * 64;
    float p[4][4];
    float mblk = -1e30f;
#pragma unroll
    for (int nf = 0; nf < 4; nf++)
#pragma unroll
      for (int j = 0; j < 4; j++) {
        int kv = kvb + nf * 16 + lg * 4 + j;
        int dq = qrow - kv;
        float s = Sa[nf][j] * SC;
        if (dq > WINDOW || dq < -WINDOW) s = -1e30f;
        p[nf][j] = s;
        mblk = fmaxf(mblk, s);
      }
    mblk = fmaxf(mblk, __shfl_xor(mblk, 16));
    mblk = fmaxf(mblk, __shfl_xor(mblk, 32));

    float mn = fmaxf(mrow, mblk);
    float scl = exp2f(mrow - mn);
    mrow = mn;

    float rsum = 0.f;
#pragma unroll
    for (int nf = 0; nf < 4; nf++)
#pragma unroll
      for (int j = 0; j < 4; j++) {
        float e = exp2f(p[nf][j] - mn);
        p[nf][j] = e;
        rsum += e;
      }
    rsum += __shfl_xor(rsum, 16);
    rsum += __shfl_xor(rsum, 32);
    lrow = lrow * scl + rsum;

    // ---- pack P into A-frags: slot e<4 = Sa[2kf][e], e>=4 = Sa[2kf+1][e-4]
    bf16x8 pa[2];
#pragma unroll
    for (int kf = 0; kf < 2; kf++)
#pragma unroll
      for (int e = 0; e < 4; e++) {
        pa[kf][e]     = (bf16)p[2 * kf][e];
        pa[kf][e + 4] = (bf16)p[2 * kf + 1][e];
      }

    // ---- rescale O (O rows are q = lg*4+j -> fetch scl from lane lg*4+j)
#pragma unroll
    for (int j = 0; j < 4; j++) {
      float so = __shfl(scl, lg * 4 + j);
#pragma unroll
      for (int nf = 0; nf < 4; nf++) Oa[nf][j] *= so;
    }

    // ---- PV: wait tr-reads (rule #18: fence + sched_barrier), 8 MFMA
    asm volatile("s_waitcnt lgkmcnt(0)" ::: "memory");
    __builtin_amdgcn_sched_barrier(0);
#pragma unroll
    for (int nf = 0; nf < 4; nf++)
#pragma unroll
      for (int kf = 0; kf < 2; kf++) {
        bf16x8 vb;
#pragma unroll
        for (int e = 0; e < 4; e++) {
          vb[e]     = tr0[nf][kf][e];
          vb[e + 4] = tr1[nf][kf][e];
        }
        Oa[nf] = __builtin_amdgcn_mfma_f32_16x16x32_bf16(pa[kf], vb, Oa[nf], 0, 0, 0);
      }

    asm volatile("s_waitcnt vmcnt(0)" ::: "memory");
    BAR();
  }

  // ---- epilogue: out[q][h*64+d]; O lane holds q = lg*4+j rows, d = nf*16+lr
  float lo[4];
#pragma unroll
  for (int j = 0; j < 4; j++) lo[j] = __shfl(lrow, lg * 4 + j);
#pragma unroll
  for (int nf = 0; nf < 4; nf++) {
#pragma unroll
    for (int j = 0; j < 4; j++) {
      int q = q0 + w * 16 + lg * 4 + j;
      int d = nf * 16 + lr;
      out[(size_t)(b * TT + q) * DIMC + h * HD + d] = (bf16)(Oa[nf][j] / lo[j]);
    }
  }
}

// ---------------------------------------------------------------- launch
extern "C" void kernel_launch(void* const* d_in, const int* in_sizes, int n_in,
                              void* d_out, int out_size, void* d_ws, size_t ws_size,
                              hipStream_t stream) {
  const float* x     = (const float*)d_in[0];
  const float* Wqkv  = (const float*)d_in[1];
  const float* Wproj = (const float*)d_in[2];
  const float* bproj = (const float*)d_in[3];
  float* out = (float*)d_out;

  char* ws = (char*)d_ws;
  bf16* xb   = (bf16*)(ws);
  bf16* wqb  = (bf16*)(ws + 8388608);
  bf16* wpb  = (bf16*)(ws + 14680064);
  bf16* qkvb = (bf16*)(ws + 16777216);
  bf16* aob  = (bf16*)(ws + 41943040);

  cast3_kernel<<<2048, 256, 0, stream>>>(x, Wqkv, Wproj, xb, wqb, wpb);
  gemm256_qkv_kernel<<<256, 512, 0, stream>>>(xb, wqb, qkvb);
  attn_kernel<<<1024, 256, 0, stream>>>(qkvb, aob);
  gemm_bt_kernel<DIMC><<<dim3(32 * 8), 256, 0, stream>>>(aob, wpb, out, bproj);
}